// Round 7
// baseline (133.992 us; speedup 1.0000x reference)
//
#include <hip/hip_runtime.h>
#include <hip/hip_bf16.h>

// Head: x[8,2048,768] fp32; Wk,Wq,Wv [768,64] fp32 -> out[8,2048,64] fp32
// q=xWq k=xWk v=xWv; att=softmax(q k^T/8); out=att v   (no causal mask)
//
// R7: TLP x2 on both kernels.
//  - attn: swapped QK^T lane-local softmax (R6 math), 8 key-split waves/block
//    (256 keys each), 512x512 grid -> 4 waves/SIMD; padded f32 combine.
//  - proj: (row-tile, o, K-half) split: 3072 blocks x 2 waves; 12 VMEM/step
//    per wave; LDS K-half combine; XCD swizzle keeps rt's 3 o-blocks local.

#define SEQ   2048
#define CEMB  768
// 0.125 (1/sqrt(64)) * log2(e): folded into q at proj epilogue
#define SCL 0.18033688011112042f
#define THR 11.0f   // defer-max threshold in exp2 units (~e^7.6)
#define NTILES 4    // K-tiles of 64 per attn wave

typedef __attribute__((ext_vector_type(4))) float f32x4;
typedef __attribute__((ext_vector_type(4))) float fvec4;
typedef __attribute__((ext_vector_type(8))) short short8;
typedef __attribute__((ext_vector_type(4))) short short4v;
typedef __attribute__((ext_vector_type(2))) unsigned int u32x2;
typedef __attribute__((ext_vector_type(4))) unsigned int u32x4;

#define MFMA32 __builtin_amdgcn_mfma_f32_16x16x32_bf16

__device__ __forceinline__ unsigned short f2bf(float f) {
    unsigned int u = __builtin_bit_cast(unsigned int, f);
    u += 0x7fffu + ((u >> 16) & 1u);   // RNE
    return (unsigned short)(u >> 16);
}
// pack two floats to bf16x2 (round-to-nearest, ties-away): cheap (5 ops)
__device__ __forceinline__ unsigned int pack_bf2(float lo, float hi) {
    unsigned int ulo = __builtin_bit_cast(unsigned int, lo);
    unsigned int uhi = __builtin_bit_cast(unsigned int, hi);
    return ((uhi + 0x8000u) & 0xffff0000u) | ((ulo + 0x8000u) >> 16);
}

// ---------------- kernel 1: W -> W^T bf16  (wt[3][64][768]) ----------------
__global__ void wt_kernel(const float* __restrict__ Wq, const float* __restrict__ Wk,
                          const float* __restrict__ Wv, unsigned short* __restrict__ wt) {
    int idx = blockIdx.x * 256 + threadIdx.x;   // 3*64*768 = 147456
    int o = idx / 49152;
    int r = idx % 49152;
    int n = r / 768;
    int k = r % 768;
    const float* W = (o == 0) ? Wq : (o == 1) ? Wk : Wv;
    wt[idx] = f2bf(W[k * 64 + n]);
}

// ---- kernel 2: proj, block=(rt,o), 2 K-half waves, LDS combine -----------
__global__ __launch_bounds__(128, 5) void proj_kernel(
        const float* __restrict__ x, const unsigned short* __restrict__ wt,
        unsigned short* __restrict__ qg, unsigned short* __restrict__ kg,
        unsigned short* __restrict__ vtg) {
    __shared__ __align__(16) float pc[16][64];              // 4 KB partials
    __shared__ __align__(16) unsigned short scratch[1280];  // 2.5 KB repack

    const int tid = threadIdx.x;
    const int lane = tid & 63;
    const int kw = tid >> 6;      // K-half 0/1
    const int l15 = lane & 15;
    const int lq = lane >> 4;

    // XCD swizzle: 3072 blocks / 8 XCDs = 384 each; (rt-major, o-minor) order
    // so one rt's 3 o-blocks are consecutive on the SAME XCD (x L2-shared).
    const int swz = (blockIdx.x & 7) * 384 + (blockIdx.x >> 3);
    const int rt = swz / 3;
    const int o = swz - rt * 3;   // 0=q 1=k 2=v
    const int row0 = rt * 16;

    f32x4 acc[4];
    #pragma unroll
    for (int f = 0; f < 4; ++f) acc[f] = f32x4{0.f, 0.f, 0.f, 0.f};

    const unsigned short* wbase = wt + o * 49152;
    const float* xr = &x[(size_t)(row0 + l15) * CEMB + kw * 384 + lq * 8];

    #pragma unroll
    for (int s = 0; s < 6; ++s) {
        const int k0 = s * 64;
        fvec4 x0 = *reinterpret_cast<const fvec4*>(xr + k0);
        fvec4 x1 = *reinterpret_cast<const fvec4*>(xr + k0 + 4);
        fvec4 x2 = *reinterpret_cast<const fvec4*>(xr + k0 + 32);
        fvec4 x3 = *reinterpret_cast<const fvec4*>(xr + k0 + 36);
        short8 a0, a1;
        #pragma unroll
        for (int j = 0; j < 4; ++j) {
            a0[j]     = (short)f2bf(x0[j]);
            a0[4 + j] = (short)f2bf(x1[j]);
            a1[j]     = (short)f2bf(x2[j]);
            a1[4 + j] = (short)f2bf(x3[j]);
        }
        #pragma unroll
        for (int f = 0; f < 4; ++f) {
            const unsigned short* wp = &wbase[(f * 16 + l15) * CEMB + kw * 384 + k0 + lq * 8];
            short8 b0 = *reinterpret_cast<const short8*>(wp);
            short8 b1 = *reinterpret_cast<const short8*>(wp + 32);
            acc[f] = MFMA32(a0, b0, acc[f], 0, 0, 0);
            acc[f] = MFMA32(a1, b1, acc[f], 0, 0, 0);
        }
    }

    if (kw == 1) {
        #pragma unroll
        for (int f = 0; f < 4; ++f)
            #pragma unroll
            for (int r = 0; r < 4; ++r)
                pc[lq * 4 + r][f * 16 + l15] = acc[f][r];
    }
    __syncthreads();
    if (kw == 0) {
        #pragma unroll
        for (int f = 0; f < 4; ++f)
            #pragma unroll
            for (int r = 0; r < 4; ++r)
                acc[f][r] += pc[lq * 4 + r][f * 16 + l15];

        if (o < 2) {
            // q (scaled) / k: repack via wave-local scratch -> 16B stores
            const float sc = o ? 1.f : SCL;
            unsigned short (*sq)[80] = reinterpret_cast<unsigned short (*)[80]>(&scratch[0]);
            #pragma unroll
            for (int f = 0; f < 4; ++f)
                #pragma unroll
                for (int r = 0; r < 4; ++r)
                    sq[lq * 4 + r][f * 16 + l15] = f2bf(acc[f][r] * sc);
            unsigned short* dst = o ? kg : qg;
            #pragma unroll
            for (int i = 0; i < 2; ++i) {
                int chunk = lane + 64 * i;
                int m = chunk >> 3;
                int c0 = (chunk & 7) * 8;
                *reinterpret_cast<short8*>(&dst[(size_t)(row0 + m) * 64 + c0]) =
                    *reinterpret_cast<const short8*>(&sq[m][c0]);
            }
        } else {
            // v transposed -> vtg[b][h][t]
            unsigned short (*lv)[20] = reinterpret_cast<unsigned short (*)[20]>(&scratch[0]);
            #pragma unroll
            for (int f = 0; f < 4; ++f)
                #pragma unroll
                for (int r = 0; r < 4; ++r)
                    lv[f * 16 + l15][lq * 4 + r] = f2bf(acc[f][r]);
            const int bb = row0 >> 11;
            const int t0 = row0 & 2047;
            unsigned short* vp = &vtg[(size_t)bb * 64 * SEQ + (size_t)lane * SEQ + t0];
            *reinterpret_cast<short8*>(vp)     = *reinterpret_cast<const short8*>(&lv[lane][0]);
            *reinterpret_cast<short8*>(vp + 8) = *reinterpret_cast<const short8*>(&lv[lane][8]);
        }
    }
}

// ---- kernel 3: flash attention, swapped-QK lane-local softmax ------------
#define LOADK(DST, T) do {                                                          \
    _Pragma("unroll")                                                               \
    for (int kb_ = 0; kb_ < 4; ++kb_) {                                             \
        const unsigned short* kp_ = kbase + (size_t)((T) * 64 + kb_ * 16 + l15) * 64; \
        DST[kb_ * 2]     = *reinterpret_cast<const short8*>(kp_ + lq * 8);          \
        DST[kb_ * 2 + 1] = *reinterpret_cast<const short8*>(kp_ + 32 + lq * 8);     \
    }                                                                               \
} while (0)

#if __has_builtin(__builtin_amdgcn_mfma_f32_16x16x16bf16_1k)
#define HAVE_MFMA16 1
#define MFMA16 __builtin_amdgcn_mfma_f32_16x16x16bf16_1k
#else
#define HAVE_MFMA16 0
#endif

#define ITER(KC, KN, T) do {                                                        \
    if ((T) + 1 < NTILES) LOADK(KN, (T) + 1);                                       \
    PVLOAD(T);                                                                      \
    f32x4 st0[4], st1[4];                                                           \
    _Pragma("unroll")                                                               \
    for (int kb = 0; kb < 4; ++kb) {                                                \
        f32x4 z = {0.f, 0.f, 0.f, 0.f};                                             \
        st0[kb] = MFMA32(KC[kb * 2], bq00, z, 0, 0, 0);                             \
        st0[kb] = MFMA32(KC[kb * 2 + 1], bq01, st0[kb], 0, 0, 0);                   \
        st1[kb] = MFMA32(KC[kb * 2], bq10, z, 0, 0, 0);                             \
        st1[kb] = MFMA32(KC[kb * 2 + 1], bq11, st1[kb], 0, 0, 0);                   \
    }                                                                               \
    f32x4 mx0 = vmax4(vmax4(st0[0], st0[1]), vmax4(st0[2], st0[3]));                \
    f32x4 mx1 = vmax4(vmax4(st1[0], st1[1]), vmax4(st1[2], st1[3]));                \
    float p0 = fmaxf(fmaxf(mx0[0], mx0[1]), fmaxf(mx0[2], mx0[3]));                 \
    float p1 = fmaxf(fmaxf(mx1[0], mx1[1]), fmaxf(mx1[2], mx1[3]));                 \
    p0 = fmaxf(p0, __shfl_xor(p0, 16)); p0 = fmaxf(p0, __shfl_xor(p0, 32));         \
    p1 = fmaxf(p1, __shfl_xor(p1, 16)); p1 = fmaxf(p1, __shfl_xor(p1, 32));         \
    if (__any((p0 > m0 + THR) || (p1 > m1 + THR))) {                                \
        float mn0 = fmaxf(m0, p0), mn1 = fmaxf(m1, p1);                             \
        float al0 = exp2f(m0 - mn0), al1 = exp2f(m1 - mn1);                         \
        m0 = mn0; m1 = mn1; l0 *= al0; l1 *= al1;                                   \
        _Pragma("unroll")                                                           \
        for (int hb = 0; hb < 4; ++hb) {                                            \
            _Pragma("unroll")                                                       \
            for (int r = 0; r < 4; ++r) { acc0[hb][r] *= al0; acc1[hb][r] *= al1; } \
        }                                                                           \
    }                                                                               \
    unsigned int w0[4][2], w1[4][2];                                                \
    _Pragma("unroll")                                                               \
    for (int kb = 0; kb < 4; ++kb) {                                                \
        float e0 = exp2f(st0[kb][0] - m0), e1 = exp2f(st0[kb][1] - m0);             \
        float e2 = exp2f(st0[kb][2] - m0), e3 = exp2f(st0[kb][3] - m0);             \
        l0 += (e0 + e1) + (e2 + e3);                                                \
        w0[kb][0] = pack_bf2(e0, e1); w0[kb][1] = pack_bf2(e2, e3);                 \
        float g0 = exp2f(st1[kb][0] - m1), g1 = exp2f(st1[kb][1] - m1);             \
        float g2 = exp2f(st1[kb][2] - m1), g3 = exp2f(st1[kb][3] - m1);             \
        l1 += (g0 + g1) + (g2 + g3);                                                \
        w1[kb][0] = pack_bf2(g0, g1); w1[kb][1] = pack_bf2(g2, g3);                 \
    }                                                                               \
    PVACC(w0, acc0); PVACC(w1, acc1);                                               \
} while (0)

#if HAVE_MFMA16
// P frag (keys kb*16+lq*4+{0..3}, q=l15) is exactly the 16x16x16 B layout.
#define PVLOAD(T)                                                                   \
    short4v va[16];                                                                 \
    _Pragma("unroll")                                                               \
    for (int hb_ = 0; hb_ < 4; ++hb_) {                                             \
        const unsigned short* vr_ = vbase + (size_t)(hb_ * 16 + l15) * SEQ + (T) * 64; \
        _Pragma("unroll")                                                           \
        for (int kb_ = 0; kb_ < 4; ++kb_)                                           \
            va[hb_ * 4 + kb_] =                                                     \
                *reinterpret_cast<const short4v*>(vr_ + kb_ * 16 + lq * 4);         \
    }
#define PVACC(W, ACC) do {                                                          \
    _Pragma("unroll")                                                               \
    for (int hb = 0; hb < 4; ++hb) {                                                \
        f32x4 a = ACC[hb];                                                          \
        _Pragma("unroll")                                                           \
        for (int kb = 0; kb < 4; ++kb) {                                            \
            u32x2 uv; uv[0] = W[kb][0]; uv[1] = W[kb][1];                           \
            a = MFMA16(va[hb * 4 + kb], __builtin_bit_cast(short4v, uv), a, 0, 0, 0); \
        }                                                                           \
        ACC[hb] = a;                                                                \
    }                                                                               \
} while (0)
#else
// Fallback: redistribute P to 16x16x32 B layout with 2 shfl + select per word.
#define PVLOAD(T)                                                                   \
    short8 va[8];                                                                   \
    _Pragma("unroll")                                                               \
    for (int hb_ = 0; hb_ < 4; ++hb_) {                                             \
        const unsigned short* vr_ = vbase + (size_t)(hb_ * 16 + l15) * SEQ + (T) * 64; \
        _Pragma("unroll")                                                           \
        for (int h_ = 0; h_ < 2; ++h_)                                              \
            va[hb_ * 2 + h_] =                                                      \
                *reinterpret_cast<const short8*>(vr_ + h_ * 32 + lq * 8);           \
    }
#define PVACC(W, ACC) do {                                                          \
    _Pragma("unroll")                                                               \
    for (int h = 0; h < 2; ++h) {                                                   \
        u32x4 bw;                                                                   \
        _Pragma("unroll")                                                           \
        for (int mw = 0; mw < 4; ++mw) {                                            \
            int src = l15 + ((((lq & 1) * 2) + (mw >> 1)) << 4);                    \
            unsigned int r1 = (unsigned int)__shfl((int)W[h * 2][mw & 1], src);     \
            unsigned int r2 = (unsigned int)__shfl((int)W[h * 2 + 1][mw & 1], src); \
            bw[mw] = (lq >> 1) ? r2 : r1;                                           \
        }                                                                           \
        short8 bp = __builtin_bit_cast(short8, bw);                                 \
        _Pragma("unroll")                                                           \
        for (int hb = 0; hb < 4; ++hb)                                              \
            ACC[hb] = MFMA32(va[hb * 2 + h], bp, ACC[hb], 0, 0, 0);                 \
    }                                                                               \
} while (0)
#endif

__device__ __forceinline__ f32x4 vmax4(f32x4 a, f32x4 b) {
    f32x4 r;
    r[0] = fmaxf(a[0], b[0]); r[1] = fmaxf(a[1], b[1]);
    r[2] = fmaxf(a[2], b[2]); r[3] = fmaxf(a[3], b[3]);
    return r;
}

__global__ __launch_bounds__(512, 4) void attn_kernel(
        const unsigned short* __restrict__ qg, const unsigned short* __restrict__ kg,
        const unsigned short* __restrict__ vtg, float* __restrict__ out) {
    __shared__ __align__(16) float oF[8][32][68];   // 69.6 KB (pad: 2-way only)
    __shared__ float mF[8][32];
    __shared__ float lF[8][32];

    const int tid = threadIdx.x;
    const int lane = tid & 63;
    const int kw = tid >> 6;          // key-split wave: keys [kw*256, +256)
    const int l15 = lane & 15;
    const int lq = lane >> 4;

    // XCD swizzle (512 % 8 == 0 -> bijective): one batch per XCD
    const int swz = (blockIdx.x & 7) * 64 + (blockIdx.x >> 3);
    const int b = swz >> 6;           // batch
    const int qt = swz & 63;          // 32-row q tile
    const size_t qrow0 = (size_t)b * SEQ + (size_t)qt * 32;

    const unsigned short* kbase = kg + ((size_t)b * SEQ + (size_t)kw * 256) * 64;
    const unsigned short* vbase = vtg + (size_t)b * 64 * SEQ + (size_t)kw * 256;

    // Q as B-operand (pre-scaled by SCL in proj): lane holds Q[q=l15][d slice]
    const short8 bq00 = *reinterpret_cast<const short8*>(&qg[(qrow0 + l15) * 64 + lq * 8]);
    const short8 bq01 = *reinterpret_cast<const short8*>(&qg[(qrow0 + l15) * 64 + 32 + lq * 8]);
    const short8 bq10 = *reinterpret_cast<const short8*>(&qg[(qrow0 + 16 + l15) * 64 + lq * 8]);
    const short8 bq11 = *reinterpret_cast<const short8*>(&qg[(qrow0 + 16 + l15) * 64 + 32 + lq * 8]);

    f32x4 acc0[4], acc1[4];   // out^T: acc[hb][r] = out[q][hb*16+lq*4+r]
    #pragma unroll
    for (int hb = 0; hb < 4; ++hb) {
        acc0[hb] = f32x4{0.f, 0.f, 0.f, 0.f};
        acc1[hb] = f32x4{0.f, 0.f, 0.f, 0.f};
    }
    float m0 = -3e38f, m1 = -3e38f, l0 = 0.f, l1 = 0.f;

    short8 kaA[8], kaB[8];
    LOADK(kaA, 0);
    #pragma unroll
    for (int it = 0; it < NTILES; it += 2) {
        ITER(kaA, kaB, it);
        ITER(kaB, kaA, it + 1);
    }

    // reduce l across the 4-lane q-group (disjoint key subsets)
    l0 += __shfl_xor(l0, 16); l0 += __shfl_xor(l0, 32);
    l1 += __shfl_xor(l1, 16); l1 += __shfl_xor(l1, 32);

    mF[kw][l15] = m0; mF[kw][16 + l15] = m1;
    lF[kw][l15] = l0; lF[kw][16 + l15] = l1;
    #pragma unroll
    for (int hb = 0; hb < 4; ++hb)
        #pragma unroll
        for (int r = 0; r < 4; ++r) {
            oF[kw][l15][hb * 16 + lq * 4 + r] = acc0[hb][r];
            oF[kw][16 + l15][hb * 16 + lq * 4 + r] = acc1[hb][r];
        }
    __syncthreads();

    // combine 8 key-split partials: 512 thr = 32 rows x 16 col-quads
    const int row = tid >> 4;
    const int c0 = (tid & 15) * 4;
    float M = mF[0][row];
    #pragma unroll
    for (int w = 1; w < 8; ++w) M = fmaxf(M, mF[w][row]);
    float L = 0.f;
    fvec4 s0 = {0.f, 0.f, 0.f, 0.f};
    #pragma unroll
    for (int w = 0; w < 8; ++w) {
        float e = exp2f(mF[w][row] - M);
        L += lF[w][row] * e;
        s0 += e * *reinterpret_cast<const fvec4*>(&oF[w][row][c0]);
    }
    float inv = 1.0f / L;
    *reinterpret_cast<fvec4*>(&out[(qrow0 + row) * 64 + c0]) = s0 * inv;
}

extern "C" void kernel_launch(void* const* d_in, const int* in_sizes, int n_in,
                              void* d_out, int out_size, void* d_ws, size_t ws_size,
                              hipStream_t stream) {
    (void)in_sizes; (void)n_in; (void)out_size; (void)ws_size;
    const float* x  = (const float*)d_in[0];
    const float* Wk = (const float*)d_in[1];   // setup_inputs order: x, Wk, Wq, Wv
    const float* Wq = (const float*)d_in[2];
    const float* Wv = (const float*)d_in[3];
    float* out = (float*)d_out;

    unsigned short* ws = (unsigned short*)d_ws;
    unsigned short* qg  = ws;                      // 16384*64
    unsigned short* kg  = ws + 1048576;            // 16384*64
    unsigned short* vtg = ws + 2097152;            // 8*64*2048
    unsigned short* wt  = ws + 3145728;            // 3*64*768

    wt_kernel<<<576, 256, 0, stream>>>(Wq, Wk, Wv, wt);
    proj_kernel<<<3072, 128, 0, stream>>>(x, wt, qg, kg, vtg);
    attn_kernel<<<512, 512, 0, stream>>>(qg, kg, vtg, out);
}

// Round 8
// 100.353 us; speedup vs baseline: 1.3352x; 1.3352x over previous
//
#include <hip/hip_runtime.h>
#include <hip/hip_bf16.h>

// Head: x[8,2048,768] fp32; Wk,Wq,Wv [768,64] fp32 -> out[8,2048,64] fp32
// q=xWq k=xWk v=xWv; att=softmax(q k^T/8); out=att v   (no causal mask)
//
// R8: R6 attn math (swapped QK^T, lane-local softmax, P in MFMA16 B-layout),
// but 8 key-split waves per 512-thr block (256 keys each), LDS-combined.
// VGPR left natural (~108) -> 4 waves/SIMD; LDS 70KB -> 2 blocks/CU -> 50% occ.
// proj: R6 verbatim (4 waves: 2 row-tiles x 2 K-halves, LDS combine).

#define SEQ   2048
#define CEMB  768
// 0.125 (1/sqrt(64)) * log2(e): folded into q at proj epilogue
#define SCL 0.18033688011112042f
#define THR 11.0f   // defer-max threshold in exp2 units (~e^7.6)
#define NTILES 4    // K-tiles of 64 per attn wave

typedef __attribute__((ext_vector_type(4))) float f32x4;
typedef __attribute__((ext_vector_type(4))) float fvec4;
typedef __attribute__((ext_vector_type(8))) short short8;
typedef __attribute__((ext_vector_type(4))) short short4v;
typedef __attribute__((ext_vector_type(2))) unsigned int u32x2;
typedef __attribute__((ext_vector_type(4))) unsigned int u32x4;

#define MFMA32 __builtin_amdgcn_mfma_f32_16x16x32_bf16

__device__ __forceinline__ unsigned short f2bf(float f) {
    unsigned int u = __builtin_bit_cast(unsigned int, f);
    u += 0x7fffu + ((u >> 16) & 1u);   // RNE
    return (unsigned short)(u >> 16);
}
// pack two floats to bf16x2 (round-to-nearest, ties-away): cheap (5 ops)
__device__ __forceinline__ unsigned int pack_bf2(float lo, float hi) {
    unsigned int ulo = __builtin_bit_cast(unsigned int, lo);
    unsigned int uhi = __builtin_bit_cast(unsigned int, hi);
    return ((uhi + 0x8000u) & 0xffff0000u) | ((ulo + 0x8000u) >> 16);
}

// ---------------- kernel 1: W -> W^T bf16  (wt[3][64][768]) ----------------
__global__ void wt_kernel(const float* __restrict__ Wq, const float* __restrict__ Wk,
                          const float* __restrict__ Wv, unsigned short* __restrict__ wt) {
    int idx = blockIdx.x * 256 + threadIdx.x;   // 3*64*768 = 147456
    int o = idx / 49152;
    int r = idx % 49152;
    int n = r / 768;
    int k = r % 768;
    const float* W = (o == 0) ? Wq : (o == 1) ? Wk : Wv;
    wt[idx] = f2bf(W[k * 64 + n]);
}

// ---- kernel 2: proj, 4 waves = 2 row-tiles x 2 K-halves, LDS combine -----
__global__ __launch_bounds__(256, 2) void proj_kernel(
        const float* __restrict__ x, const unsigned short* __restrict__ wt,
        unsigned short* __restrict__ qg, unsigned short* __restrict__ kg,
        unsigned short* __restrict__ vtg) {
    __shared__ __align__(16) float pc[2][3][16][64];            // 24 KB partials
    __shared__ __align__(16) unsigned short scratch[2][1280];   // 5 KB repack

    const int tid = threadIdx.x;
    const int lane = tid & 63;
    const int wv = tid >> 6;
    const int rw = wv >> 1;     // row-tile 0/1
    const int kw = wv & 1;      // K-half 0/1
    const int l15 = lane & 15;
    const int lq = lane >> 4;
    const int row0 = blockIdx.x * 32 + rw * 16;

    f32x4 acc[3][4];
    #pragma unroll
    for (int o = 0; o < 3; ++o)
        #pragma unroll
        for (int f = 0; f < 4; ++f) acc[o][f] = f32x4{0.f, 0.f, 0.f, 0.f};

    const float* xr = &x[(size_t)(row0 + l15) * CEMB + kw * 384 + lq * 8];

    #pragma unroll
    for (int s = 0; s < 6; ++s) {
        const int k0 = s * 64;
        fvec4 x0 = *reinterpret_cast<const fvec4*>(xr + k0);
        fvec4 x1 = *reinterpret_cast<const fvec4*>(xr + k0 + 4);
        fvec4 x2 = *reinterpret_cast<const fvec4*>(xr + k0 + 32);
        fvec4 x3 = *reinterpret_cast<const fvec4*>(xr + k0 + 36);
        short8 a0, a1;
        #pragma unroll
        for (int j = 0; j < 4; ++j) {
            a0[j]     = (short)f2bf(x0[j]);
            a0[4 + j] = (short)f2bf(x1[j]);
            a1[j]     = (short)f2bf(x2[j]);
            a1[4 + j] = (short)f2bf(x3[j]);
        }
        #pragma unroll
        for (int o = 0; o < 3; ++o) {
            #pragma unroll
            for (int f = 0; f < 4; ++f) {
                const unsigned short* wp =
                    &wt[o * 49152 + (f * 16 + l15) * CEMB + kw * 384 + k0 + lq * 8];
                short8 b0 = *reinterpret_cast<const short8*>(wp);
                short8 b1 = *reinterpret_cast<const short8*>(wp + 32);
                acc[o][f] = MFMA32(a0, b0, acc[o][f], 0, 0, 0);
                acc[o][f] = MFMA32(a1, b1, acc[o][f], 0, 0, 0);
            }
        }
    }

    if (kw == 1) {
        #pragma unroll
        for (int o = 0; o < 3; ++o)
            #pragma unroll
            for (int f = 0; f < 4; ++f)
                #pragma unroll
                for (int r = 0; r < 4; ++r)
                    pc[rw][o][lq * 4 + r][f * 16 + l15] = acc[o][f][r];
    }
    __syncthreads();
    if (kw == 0) {
        #pragma unroll
        for (int o = 0; o < 3; ++o)
            #pragma unroll
            for (int f = 0; f < 4; ++f)
                #pragma unroll
                for (int r = 0; r < 4; ++r)
                    acc[o][f][r] += pc[rw][o][lq * 4 + r][f * 16 + l15];

        // q, k: repack in wave-local scratch (in-order LDS per wave) -> 16B stores
        unsigned short (*sq)[80] = reinterpret_cast<unsigned short (*)[80]>(&scratch[rw][0]);
        #pragma unroll
        for (int o = 0; o < 2; ++o) {
            const float sc = o ? 1.f : SCL;   // fold softmax scale into q
            #pragma unroll
            for (int f = 0; f < 4; ++f)
                #pragma unroll
                for (int r = 0; r < 4; ++r)
                    sq[lq * 4 + r][f * 16 + l15] = f2bf(acc[o][f][r] * sc);
            unsigned short* dst = o ? kg : qg;
            #pragma unroll
            for (int i = 0; i < 2; ++i) {
                int chunk = lane + 64 * i;
                int m = chunk >> 3;
                int c0 = (chunk & 7) * 8;
                *reinterpret_cast<short8*>(&dst[(size_t)(row0 + m) * 64 + c0]) =
                    *reinterpret_cast<const short8*>(&sq[m][c0]);
            }
        }
        // v transposed -> vtg[b][h][t]
        unsigned short (*lv)[20] = reinterpret_cast<unsigned short (*)[20]>(&scratch[rw][0]);
        #pragma unroll
        for (int f = 0; f < 4; ++f)
            #pragma unroll
            for (int r = 0; r < 4; ++r)
                lv[f * 16 + l15][lq * 4 + r] = f2bf(acc[2][f][r]);
        const int bb = row0 >> 11;
        const int t0 = row0 & 2047;
        unsigned short* vp = &vtg[(size_t)bb * 64 * SEQ + (size_t)lane * SEQ + t0];
        *reinterpret_cast<short8*>(vp)     = *reinterpret_cast<const short8*>(&lv[lane][0]);
        *reinterpret_cast<short8*>(vp + 8) = *reinterpret_cast<const short8*>(&lv[lane][8]);
    }
}

// ---- kernel 3: flash attention, swapped-QK lane-local softmax ------------
#define LOADK(DST, T) do {                                                          \
    _Pragma("unroll")                                                               \
    for (int kb_ = 0; kb_ < 4; ++kb_) {                                             \
        const unsigned short* kp_ = kbase + (size_t)((T) * 64 + kb_ * 16 + l15) * 64; \
        DST[kb_ * 2]     = *reinterpret_cast<const short8*>(kp_ + lq * 8);          \
        DST[kb_ * 2 + 1] = *reinterpret_cast<const short8*>(kp_ + 32 + lq * 8);     \
    }                                                                               \
} while (0)

#if __has_builtin(__builtin_amdgcn_mfma_f32_16x16x16bf16_1k)
#define HAVE_MFMA16 1
#define MFMA16 __builtin_amdgcn_mfma_f32_16x16x16bf16_1k
#else
#define HAVE_MFMA16 0
#endif

#define ITER(KC, KN, T) do {                                                        \
    if ((T) + 1 < NTILES) LOADK(KN, (T) + 1);                                       \
    PVLOAD(T);                                                                      \
    f32x4 st0[4], st1[4];                                                           \
    _Pragma("unroll")                                                               \
    for (int kb = 0; kb < 4; ++kb) {                                                \
        f32x4 z = {0.f, 0.f, 0.f, 0.f};                                             \
        st0[kb] = MFMA32(KC[kb * 2], bq00, z, 0, 0, 0);                             \
        st0[kb] = MFMA32(KC[kb * 2 + 1], bq01, st0[kb], 0, 0, 0);                   \
        st1[kb] = MFMA32(KC[kb * 2], bq10, z, 0, 0, 0);                             \
        st1[kb] = MFMA32(KC[kb * 2 + 1], bq11, st1[kb], 0, 0, 0);                   \
    }                                                                               \
    f32x4 mx0 = vmax4(vmax4(st0[0], st0[1]), vmax4(st0[2], st0[3]));                \
    f32x4 mx1 = vmax4(vmax4(st1[0], st1[1]), vmax4(st1[2], st1[3]));                \
    float p0 = fmaxf(fmaxf(mx0[0], mx0[1]), fmaxf(mx0[2], mx0[3]));                 \
    float p1 = fmaxf(fmaxf(mx1[0], mx1[1]), fmaxf(mx1[2], mx1[3]));                 \
    p0 = fmaxf(p0, __shfl_xor(p0, 16)); p0 = fmaxf(p0, __shfl_xor(p0, 32));         \
    p1 = fmaxf(p1, __shfl_xor(p1, 16)); p1 = fmaxf(p1, __shfl_xor(p1, 32));         \
    if (__any((p0 > m0 + THR) || (p1 > m1 + THR))) {                                \
        float mn0 = fmaxf(m0, p0), mn1 = fmaxf(m1, p1);                             \
        float al0 = exp2f(m0 - mn0), al1 = exp2f(m1 - mn1);                         \
        m0 = mn0; m1 = mn1; l0 *= al0; l1 *= al1;                                   \
        _Pragma("unroll")                                                           \
        for (int hb = 0; hb < 4; ++hb) {                                            \
            _Pragma("unroll")                                                       \
            for (int r = 0; r < 4; ++r) { acc0[hb][r] *= al0; acc1[hb][r] *= al1; } \
        }                                                                           \
    }                                                                               \
    unsigned int w0[4][2], w1[4][2];                                                \
    _Pragma("unroll")                                                               \
    for (int kb = 0; kb < 4; ++kb) {                                                \
        float e0 = exp2f(st0[kb][0] - m0), e1 = exp2f(st0[kb][1] - m0);             \
        float e2 = exp2f(st0[kb][2] - m0), e3 = exp2f(st0[kb][3] - m0);             \
        l0 += (e0 + e1) + (e2 + e3);                                                \
        w0[kb][0] = pack_bf2(e0, e1); w0[kb][1] = pack_bf2(e2, e3);                 \
        float g0 = exp2f(st1[kb][0] - m1), g1 = exp2f(st1[kb][1] - m1);             \
        float g2 = exp2f(st1[kb][2] - m1), g3 = exp2f(st1[kb][3] - m1);             \
        l1 += (g0 + g1) + (g2 + g3);                                                \
        w1[kb][0] = pack_bf2(g0, g1); w1[kb][1] = pack_bf2(g2, g3);                 \
    }                                                                               \
    PVACC(w0, acc0); PVACC(w1, acc1);                                               \
} while (0)

#if HAVE_MFMA16
// P frag (keys kb*16+lq*4+{0..3}, q=l15) is exactly the 16x16x16 B layout.
#define PVLOAD(T)                                                                   \
    short4v va[16];                                                                 \
    _Pragma("unroll")                                                               \
    for (int hb_ = 0; hb_ < 4; ++hb_) {                                             \
        const unsigned short* vr_ = vbase + (size_t)(hb_ * 16 + l15) * SEQ + (T) * 64; \
        _Pragma("unroll")                                                           \
        for (int kb_ = 0; kb_ < 4; ++kb_)                                           \
            va[hb_ * 4 + kb_] =                                                     \
                *reinterpret_cast<const short4v*>(vr_ + kb_ * 16 + lq * 4);         \
    }
#define PVACC(W, ACC) do {                                                          \
    _Pragma("unroll")                                                               \
    for (int hb = 0; hb < 4; ++hb) {                                                \
        f32x4 a = ACC[hb];                                                          \
        _Pragma("unroll")                                                           \
        for (int kb = 0; kb < 4; ++kb) {                                            \
            u32x2 uv; uv[0] = W[kb][0]; uv[1] = W[kb][1];                           \
            a = MFMA16(va[hb * 4 + kb], __builtin_bit_cast(short4v, uv), a, 0, 0, 0); \
        }                                                                           \
        ACC[hb] = a;                                                                \
    }                                                                               \
} while (0)
#else
// Fallback: redistribute P to 16x16x32 B layout with 2 shfl + select per word.
#define PVLOAD(T)                                                                   \
    short8 va[8];                                                                   \
    _Pragma("unroll")                                                               \
    for (int hb_ = 0; hb_ < 4; ++hb_) {                                             \
        const unsigned short* vr_ = vbase + (size_t)(hb_ * 16 + l15) * SEQ + (T) * 64; \
        _Pragma("unroll")                                                           \
        for (int h_ = 0; h_ < 2; ++h_)                                              \
            va[hb_ * 2 + h_] =                                                      \
                *reinterpret_cast<const short8*>(vr_ + h_ * 32 + lq * 8);           \
    }
#define PVACC(W, ACC) do {                                                          \
    _Pragma("unroll")                                                               \
    for (int h = 0; h < 2; ++h) {                                                   \
        u32x4 bw;                                                                   \
        _Pragma("unroll")                                                           \
        for (int mw = 0; mw < 4; ++mw) {                                            \
            int src = l15 + ((((lq & 1) * 2) + (mw >> 1)) << 4);                    \
            unsigned int r1 = (unsigned int)__shfl((int)W[h * 2][mw & 1], src);     \
            unsigned int r2 = (unsigned int)__shfl((int)W[h * 2 + 1][mw & 1], src); \
            bw[mw] = (lq >> 1) ? r2 : r1;                                           \
        }                                                                           \
        short8 bp = __builtin_bit_cast(short8, bw);                                 \
        _Pragma("unroll")                                                           \
        for (int hb = 0; hb < 4; ++hb)                                              \
            ACC[hb] = MFMA32(va[hb * 2 + h], bp, ACC[hb], 0, 0, 0);                 \
    }                                                                               \
} while (0)
#endif

__device__ __forceinline__ f32x4 vmax4(f32x4 a, f32x4 b) {
    f32x4 r;
    r[0] = fmaxf(a[0], b[0]); r[1] = fmaxf(a[1], b[1]);
    r[2] = fmaxf(a[2], b[2]); r[3] = fmaxf(a[3], b[3]);
    return r;
}

__global__ __launch_bounds__(512) void attn_kernel(
        const unsigned short* __restrict__ qg, const unsigned short* __restrict__ kg,
        const unsigned short* __restrict__ vtg, float* __restrict__ out) {
    __shared__ __align__(16) float oF[8][32][68];   // 68-pad: 2-way stores only
    __shared__ float mF[8][32];
    __shared__ float lF[8][32];

    const int tid = threadIdx.x;
    const int lane = tid & 63;
    const int kw = tid >> 6;          // key-split wave 0..7: keys [kw*256, +256)
    const int l15 = lane & 15;
    const int lq = lane >> 4;

    // XCD swizzle (512 % 8 == 0 -> bijective): one batch per XCD
    const int swz = (blockIdx.x & 7) * 64 + (blockIdx.x >> 3);
    const int b = swz >> 6;           // batch
    const int qt = swz & 63;          // 32-row q tile
    const size_t qrow0 = (size_t)b * SEQ + (size_t)qt * 32;

    const unsigned short* kbase = kg + ((size_t)b * SEQ + (size_t)kw * 256) * 64;
    const unsigned short* vbase = vtg + (size_t)b * 64 * SEQ + (size_t)kw * 256;

    // Q as B-operand (pre-scaled by SCL in proj): lane holds Q[q=l15][d slice]
    const short8 bq00 = *reinterpret_cast<const short8*>(&qg[(qrow0 + l15) * 64 + lq * 8]);
    const short8 bq01 = *reinterpret_cast<const short8*>(&qg[(qrow0 + l15) * 64 + 32 + lq * 8]);
    const short8 bq10 = *reinterpret_cast<const short8*>(&qg[(qrow0 + 16 + l15) * 64 + lq * 8]);
    const short8 bq11 = *reinterpret_cast<const short8*>(&qg[(qrow0 + 16 + l15) * 64 + 32 + lq * 8]);

    f32x4 acc0[4], acc1[4];   // out^T: acc[hb][r] = out[q][hb*16+lq*4+r]
    #pragma unroll
    for (int hb = 0; hb < 4; ++hb) {
        acc0[hb] = f32x4{0.f, 0.f, 0.f, 0.f};
        acc1[hb] = f32x4{0.f, 0.f, 0.f, 0.f};
    }
    float m0 = -3e38f, m1 = -3e38f, l0 = 0.f, l1 = 0.f;

    short8 kaA[8], kaB[8];
    LOADK(kaA, 0);
    #pragma unroll
    for (int it = 0; it < NTILES; it += 2) {
        ITER(kaA, kaB, it);
        ITER(kaB, kaA, it + 1);
    }

    // reduce l across the 4-lane q-group (disjoint key subsets)
    l0 += __shfl_xor(l0, 16); l0 += __shfl_xor(l0, 32);
    l1 += __shfl_xor(l1, 16); l1 += __shfl_xor(l1, 32);

    mF[kw][l15] = m0; mF[kw][16 + l15] = m1;
    lF[kw][l15] = l0; lF[kw][16 + l15] = l1;
    #pragma unroll
    for (int hb = 0; hb < 4; ++hb)
        #pragma unroll
        for (int r = 0; r < 4; ++r) {
            oF[kw][l15][hb * 16 + lq * 4 + r] = acc0[hb][r];
            oF[kw][16 + l15][hb * 16 + lq * 4 + r] = acc1[hb][r];
        }
    __syncthreads();

    // combine 8 key-split partials: 512 thr = 32 rows x 16 col-quads
    const int row = tid >> 4;
    const int c0 = (tid & 15) * 4;
    float M = mF[0][row];
    #pragma unroll
    for (int w = 1; w < 8; ++w) M = fmaxf(M, mF[w][row]);
    float L = 0.f;
    fvec4 s0 = {0.f, 0.f, 0.f, 0.f};
    #pragma unroll
    for (int w = 0; w < 8; ++w) {
        float e = exp2f(mF[w][row] - M);
        L += lF[w][row] * e;
        s0 += e * *reinterpret_cast<const fvec4*>(&oF[w][row][c0]);
    }
    float inv = 1.0f / L;
    *reinterpret_cast<fvec4*>(&out[(qrow0 + row) * 64 + c0]) = s0 * inv;
}

extern "C" void kernel_launch(void* const* d_in, const int* in_sizes, int n_in,
                              void* d_out, int out_size, void* d_ws, size_t ws_size,
                              hipStream_t stream) {
    (void)in_sizes; (void)n_in; (void)out_size; (void)ws_size;
    const float* x  = (const float*)d_in[0];
    const float* Wk = (const float*)d_in[1];   // setup_inputs order: x, Wk, Wq, Wv
    const float* Wq = (const float*)d_in[2];
    const float* Wv = (const float*)d_in[3];
    float* out = (float*)d_out;

    unsigned short* ws = (unsigned short*)d_ws;
    unsigned short* qg  = ws;                      // 16384*64
    unsigned short* kg  = ws + 1048576;            // 16384*64
    unsigned short* vtg = ws + 2097152;            // 8*64*2048
    unsigned short* wt  = ws + 3145728;            // 3*64*768

    wt_kernel<<<576, 256, 0, stream>>>(Wq, Wk, Wv, wt);
    proj_kernel<<<512, 256, 0, stream>>>(x, wt, qg, kg, vtg);
    attn_kernel<<<512, 512, 0, stream>>>(qg, kg, vtg, out);
}

// Round 9
// 61.908 us; speedup vs baseline: 2.1644x; 1.6210x over previous
//
#include <hip/hip_runtime.h>
#include <hip/hip_bf16.h>

// Head: x[8,2048,768] fp32; Wk,Wq,Wv [768,64] fp32 -> out[8,2048,64] fp32
// q=xWq k=xWk v=xWv; att=softmax(q k^T/8); out=att v   (no causal mask)
//
// R9: reuse-centric rewrite.
//  - proj: W^T in registers (96 VGPR/wave, one (o,f) tile per wave, 12 waves);
//    x staged once per 16-row tile into swizzled LDS (dbuf), reused by all
//    12 waves; x read once from HBM -> HBM-bound.
//  - attn: q-split waves over SHARED K/V LDS tiles (global_load_lds, dbuf,
//    XOR swizzle). Grid 256 = 8b x 16qt x 2 key-halves. Partials bf16-packed
//    into d_out words; combine kernel normalizes.

#define SEQ   2048
#define CEMB  768
// 0.125 (1/sqrt(64)) * log2(e): folded into q at proj epilogue
#define SCL 0.18033688011112042f
#define THR 11.0f

typedef __attribute__((ext_vector_type(4))) float f32x4;
typedef __attribute__((ext_vector_type(4))) float fvec4;
typedef __attribute__((ext_vector_type(8))) short short8;
typedef __attribute__((ext_vector_type(4))) short short4v;
typedef __attribute__((ext_vector_type(4))) unsigned short u16x4;
typedef __attribute__((ext_vector_type(2))) unsigned int u32x2;
typedef __attribute__((ext_vector_type(4))) unsigned int u32x4;

#define MFMA32 __builtin_amdgcn_mfma_f32_16x16x32_bf16

__device__ __forceinline__ unsigned short f2bf(float f) {
    unsigned int u = __builtin_bit_cast(unsigned int, f);
    u += 0x7fffu + ((u >> 16) & 1u);   // RNE
    return (unsigned short)(u >> 16);
}
__device__ __forceinline__ unsigned int pack_bf2(float lo, float hi) {
    unsigned int ulo = __builtin_bit_cast(unsigned int, lo);
    unsigned int uhi = __builtin_bit_cast(unsigned int, hi);
    return ((uhi + 0x8000u) & 0xffff0000u) | ((ulo + 0x8000u) >> 16);
}
__device__ __forceinline__ short8 pack8(fvec4 a, fvec4 b) {
    short8 s;
    #pragma unroll
    for (int j = 0; j < 4; ++j) {
        s[j]     = (short)f2bf(a[j]);
        s[4 + j] = (short)f2bf(b[j]);
    }
    return s;
}
__device__ __forceinline__ f32x4 vmax4(f32x4 a, f32x4 b) {
    f32x4 r;
    r[0] = fmaxf(a[0], b[0]); r[1] = fmaxf(a[1], b[1]);
    r[2] = fmaxf(a[2], b[2]); r[3] = fmaxf(a[3], b[3]);
    return r;
}
// async global->LDS, 16B per lane
__device__ __forceinline__ void gl_lds16(const void* g, void* l) {
    __builtin_amdgcn_global_load_lds(
        (const __attribute__((address_space(1))) unsigned int*)g,
        (__attribute__((address_space(3))) unsigned int*)l, 16, 0, 0);
}

// ---------------- kernel 1: W -> W^T bf16  (wt[3][64][768]) ----------------
__global__ void wt_kernel(const float* __restrict__ Wq, const float* __restrict__ Wk,
                          const float* __restrict__ Wv, unsigned short* __restrict__ wt) {
    int idx = blockIdx.x * 256 + threadIdx.x;   // 3*64*768 = 147456
    int o = idx / 49152;
    int r = idx % 49152;
    int n = r / 768;
    int k = r % 768;
    const float* W = (o == 0) ? Wq : (o == 1) ? Wk : Wv;
    wt[idx] = f2bf(W[k * 64 + n]);
}

// ---- kernel 2: proj, 12 waves=(o,f), W in regs, x LDS-staged (dbuf) ------
__global__ __launch_bounds__(768) void proj_kernel(
        const float* __restrict__ x, const unsigned short* __restrict__ wt,
        unsigned short* __restrict__ qg, unsigned short* __restrict__ kg,
        unsigned short* __restrict__ vtg) {
    __shared__ __align__(16) unsigned short xl[2][12288];   // 2 x 16rows x 96slots x 16B

    const int tid = threadIdx.x;
    const int lane = tid & 63;
    const int wv = tid >> 6;      // 0..11
    const int l15 = lane & 15;
    const int lq = lane >> 4;
    const int o = wv >> 2;        // 0=q 1=k 2=v
    const int f = wv & 3;         // 16-col tile
    const int rowbase = blockIdx.x * 64;

    // W^T tile (16 n-rows x 768 k) -> 24 A-frags in registers (96 VGPR)
    short8 wfr[24];
    #pragma unroll
    for (int s = 0; s < 24; ++s)
        wfr[s] = *reinterpret_cast<const short8*>(
            &wt[o * 49152 + (f * 16 + l15) * CEMB + s * 32 + lq * 8]);

    // stage slot geometry (constant per thread): two slots per pass
    const int S0 = tid, S1 = 768 + tid;
    const int r0 = S0 / 96, c0 = S0 - r0 * 96;
    const int r1 = S1 / 96, c1 = S1 - r1 * 96;
    const int d0 = r0 * 1536 + ((c0 ^ (r0 & 7)) << 4);
    const int d1 = r1 * 1536 + ((c1 ^ (r1 & 7)) << 4);

    // prologue: stage tile 0 into xl[0]
    {
        const float* g0 = x + (size_t)(rowbase + r0) * CEMB + c0 * 8;
        const float* g1 = x + (size_t)(rowbase + r1) * CEMB + c1 * 8;
        fvec4 a0 = *reinterpret_cast<const fvec4*>(g0);
        fvec4 a1 = *reinterpret_cast<const fvec4*>(g0 + 4);
        fvec4 b0 = *reinterpret_cast<const fvec4*>(g1);
        fvec4 b1 = *reinterpret_cast<const fvec4*>(g1 + 4);
        *reinterpret_cast<short8*>((char*)&xl[0][0] + d0) = pack8(a0, a1);
        *reinterpret_cast<short8*>((char*)&xl[0][0] + d1) = pack8(b0, b1);
    }
    __syncthreads();

    #pragma unroll
    for (int t = 0; t < 4; ++t) {
        const int cur = t & 1;
        fvec4 pA0, pA1, pB0, pB1;
        if (t < 3) {   // issue next-tile loads early (T14)
            const int base = rowbase + (t + 1) * 16;
            const float* g0 = x + (size_t)(base + r0) * CEMB + c0 * 8;
            const float* g1 = x + (size_t)(base + r1) * CEMB + c1 * 8;
            pA0 = *reinterpret_cast<const fvec4*>(g0);
            pA1 = *reinterpret_cast<const fvec4*>(g0 + 4);
            pB0 = *reinterpret_cast<const fvec4*>(g1);
            pB1 = *reinterpret_cast<const fvec4*>(g1 + 4);
        }

        // compute tile t: acc = W^T(16n x 768) * x-tile^T
        f32x4 acc = f32x4{0.f, 0.f, 0.f, 0.f};
        const char* xb = (const char*)&xl[cur][0];
        const int rswz = l15 & 7;
        #pragma unroll
        for (int s = 0; s < 24; ++s) {
            short8 bf = *reinterpret_cast<const short8*>(
                xb + l15 * 1536 + (((s * 4 + lq) ^ rswz) << 4));
            acc = MFMA32(wfr[s], bf, acc, 0, 0, 0);
        }

        // epilogue: lane holds out[xrow = rowbase+t*16+l15][n = f*16+lq*4+r]
        const int xrow = rowbase + t * 16 + l15;
        if (o < 2) {
            const float sc = o ? 1.f : SCL;
            u16x4 st;
            #pragma unroll
            for (int r = 0; r < 4; ++r) st[r] = f2bf(acc[r] * sc);
            unsigned short* dst = (o ? kg : qg) + (size_t)xrow * 64 + f * 16 + lq * 4;
            *reinterpret_cast<u16x4*>(dst) = st;
        } else {
            const int bb = xrow >> 11;
            const int tt = xrow & 2047;
            #pragma unroll
            for (int r = 0; r < 4; ++r)
                vtg[(size_t)bb * 131072 + (size_t)(f * 16 + lq * 4 + r) * SEQ + tt] =
                    f2bf(acc[r]);
        }

        if (t < 3) {   // write next tile into the other buffer
            *reinterpret_cast<short8*>((char*)&xl[cur ^ 1][0] + d0) = pack8(pA0, pA1);
            *reinterpret_cast<short8*>((char*)&xl[cur ^ 1][0] + d1) = pack8(pB0, pB1);
        }
        __syncthreads();
    }
}

// ---- kernel 3: attn, shared K/V LDS tiles, swapped-QK lane-local softmax --
#if __has_builtin(__builtin_amdgcn_mfma_f32_16x16x16bf16_1k)
#define HAVE_MFMA16 1
#define MFMA16 __builtin_amdgcn_mfma_f32_16x16x16bf16_1k
#else
#define HAVE_MFMA16 0
#endif

__global__ __launch_bounds__(512) void attn_kernel(
        const unsigned short* __restrict__ qg, const unsigned short* __restrict__ kg,
        const unsigned short* __restrict__ vtg, float* __restrict__ out,
        float* __restrict__ pm, float* __restrict__ pl) {
    __shared__ __align__(16) unsigned short kbuf[2][4096];   // [64 key][64 d] swz
    __shared__ __align__(16) unsigned short vbuf[2][4096];   // [64 d][64 key] swz

    const int tid = threadIdx.x;
    const int lane = tid & 63;
    const int wv = tid >> 6;      // q-subtile wave 0..7
    const int l15 = lane & 15;
    const int lq = lane >> 4;

    // XCD swizzle: 256 blocks, 32/XCD = one batch per XCD
    const int swz = (blockIdx.x & 7) * 32 + (blockIdx.x >> 3);
    const int b = swz >> 5;
    const int qt = (swz >> 1) & 15;   // 128-row q tile
    const int ks = swz & 1;           // key half
    const int qrow0 = b * SEQ + qt * 128 + wv * 16;

    const unsigned short* kgb = kg + (size_t)(b * SEQ + ks * 1024) * 64;
    const unsigned short* vgb = vtg + (size_t)b * 131072 + ks * 1024;

    // staging geometry: 512 threads x 16B cover one 8KB tile
    const int srow = tid >> 3;            // 0..63
    const int ssw = ((tid & 7) ^ (srow & 7)) * 8;   // pre-swizzled src (ushort)
    #define STAGE(S, KT) do {                                                   \
        gl_lds16(kgb + (size_t)((KT) * 64 + srow) * 64 + ssw, &kbuf[S][tid * 8]); \
        gl_lds16(vgb + (size_t)srow * SEQ + (KT) * 64 + ssw, &vbuf[S][tid * 8]);  \
    } while (0)

    // Q as B-operand (pre-scaled): lane holds Q[q=l15][d slice]
    const short8 bq0 = *reinterpret_cast<const short8*>(&qg[(size_t)(qrow0 + l15) * 64 + lq * 8]);
    const short8 bq1 = *reinterpret_cast<const short8*>(&qg[(size_t)(qrow0 + l15) * 64 + 32 + lq * 8]);

    f32x4 acc[4];
    #pragma unroll
    for (int hb = 0; hb < 4; ++hb) acc[hb] = f32x4{0.f, 0.f, 0.f, 0.f};
    float m = -3e38f, l = 0.f;

    STAGE(0, 0);
    __syncthreads();

    #define ITERL(S) do {                                                            \
        const char* kb_ = (const char*)&kbuf[S][0];                                  \
        const char* vb_ = (const char*)&vbuf[S][0];                                  \
        short8 kf[8];                                                                \
        _Pragma("unroll")                                                            \
        for (int kb = 0; kb < 4; ++kb) {                                             \
            const int row = kb * 16 + l15, rs = row & 7, rb = row * 128;             \
            kf[2 * kb]     = *reinterpret_cast<const short8*>(kb_ + rb + ((lq ^ rs) << 4));       \
            kf[2 * kb + 1] = *reinterpret_cast<const short8*>(kb_ + rb + (((lq + 4) ^ rs) << 4)); \
        }                                                                            \
        PVLOAD_L;                                                                    \
        f32x4 st[4];                                                                 \
        _Pragma("unroll")                                                            \
        for (int kb = 0; kb < 4; ++kb) {                                             \
            f32x4 z = {0.f, 0.f, 0.f, 0.f};                                          \
            st[kb] = MFMA32(kf[2 * kb], bq0, z, 0, 0, 0);                            \
            st[kb] = MFMA32(kf[2 * kb + 1], bq1, st[kb], 0, 0, 0);                   \
        }                                                                            \
        f32x4 mx = vmax4(vmax4(st[0], st[1]), vmax4(st[2], st[3]));                  \
        float p = fmaxf(fmaxf(mx[0], mx[1]), fmaxf(mx[2], mx[3]));                   \
        p = fmaxf(p, __shfl_xor(p, 16)); p = fmaxf(p, __shfl_xor(p, 32));            \
        if (__any(p > m + THR)) {                                                    \
            float mn = fmaxf(m, p);                                                  \
            float al = exp2f(m - mn);                                                \
            m = mn; l *= al;                                                         \
            _Pragma("unroll")                                                        \
            for (int hb = 0; hb < 4; ++hb)                                           \
                _Pragma("unroll")                                                    \
                for (int r = 0; r < 4; ++r) acc[hb][r] *= al;                        \
        }                                                                            \
        unsigned int w[4][2];                                                        \
        _Pragma("unroll")                                                            \
        for (int kb = 0; kb < 4; ++kb) {                                             \
            float e0 = exp2f(st[kb][0] - m), e1 = exp2f(st[kb][1] - m);              \
            float e2 = exp2f(st[kb][2] - m), e3 = exp2f(st[kb][3] - m);              \
            l += (e0 + e1) + (e2 + e3);                                              \
            w[kb][0] = pack_bf2(e0, e1); w[kb][1] = pack_bf2(e2, e3);                \
        }                                                                            \
        PVACC_L;                                                                     \
    } while (0)

#if HAVE_MFMA16
    #define PVLOAD_L                                                                 \
        short4v va[16];                                                              \
        _Pragma("unroll")                                                            \
        for (int hb = 0; hb < 4; ++hb) {                                             \
            const int row = hb * 16 + l15, rs = row & 7, rb = row * 128;             \
            _Pragma("unroll")                                                        \
            for (int kb = 0; kb < 4; ++kb)                                           \
                va[hb * 4 + kb] = *reinterpret_cast<const short4v*>(                 \
                    vb_ + rb + (((kb * 2 + (lq >> 1)) ^ rs) << 4) + (lq & 1) * 8);   \
        }
    #define PVACC_L do {                                                             \
        _Pragma("unroll")                                                            \
        for (int hb = 0; hb < 4; ++hb) {                                             \
            f32x4 a = acc[hb];                                                       \
            _Pragma("unroll")                                                        \
            for (int kb = 0; kb < 4; ++kb) {                                         \
                u32x2 uv; uv[0] = w[kb][0]; uv[1] = w[kb][1];                        \
                a = MFMA16(va[hb * 4 + kb], __builtin_bit_cast(short4v, uv), a, 0, 0, 0); \
            }                                                                        \
            acc[hb] = a;                                                             \
        }                                                                            \
    } while (0)
#else
    #define PVLOAD_L                                                                 \
        short8 va[8];                                                                \
        _Pragma("unroll")                                                            \
        for (int hb = 0; hb < 4; ++hb) {                                             \
            const int row = hb * 16 + l15, rs = row & 7, rb = row * 128;             \
            _Pragma("unroll")                                                        \
            for (int h = 0; h < 2; ++h)                                              \
                va[hb * 2 + h] = *reinterpret_cast<const short8*>(                   \
                    vb_ + rb + (((h * 4 + lq) ^ rs) << 4));                          \
        }
    #define PVACC_L do {                                                             \
        _Pragma("unroll")                                                            \
        for (int h = 0; h < 2; ++h) {                                                \
            u32x4 bw;                                                                \
            _Pragma("unroll")                                                        \
            for (int mw = 0; mw < 4; ++mw) {                                         \
                int src = l15 + ((((lq & 1) * 2) + (mw >> 1)) << 4);                 \
                unsigned int r1 = (unsigned int)__shfl((int)w[h * 2][mw & 1], src);  \
                unsigned int r2 = (unsigned int)__shfl((int)w[h * 2 + 1][mw & 1], src); \
                bw[mw] = (lq >> 1) ? r2 : r1;                                        \
            }                                                                        \
            short8 bp = __builtin_bit_cast(short8, bw);                              \
            _Pragma("unroll")                                                        \
            for (int hb = 0; hb < 4; ++hb)                                           \
                acc[hb] = MFMA32(va[hb * 2 + h], bp, acc[hb], 0, 0, 0);              \
        }                                                                            \
    } while (0)
#endif

    #pragma unroll
    for (int kt2 = 0; kt2 < 8; ++kt2) {
        const int t0 = kt2 * 2;
        if (t0 + 1 < 16) STAGE(1, t0 + 1);
        ITERL(0);
        __syncthreads();
        if (t0 + 2 < 16) STAGE(0, t0 + 2);
        ITERL(1);
        __syncthreads();
    }

    // l across the 4-lane q-group (disjoint key subsets)
    l += __shfl_xor(l, 16); l += __shfl_xor(l, 32);

    // partial write: bf16 halves packed into d_out words (ks selects half)
    const int q = qrow0 + l15;
    char* ob = (char*)out;
    #pragma unroll
    for (int hb = 0; hb < 4; ++hb)
        #pragma unroll
        for (int r = 0; r < 4; ++r) {
            const int col = hb * 16 + lq * 4 + r;
            *reinterpret_cast<unsigned short*>(ob + ((size_t)q * 64 + col) * 4 + ks * 2) =
                f2bf(acc[hb][r]);
        }
    pm[ks * 16384 + q] = m;
    pl[ks * 16384 + q] = l;
    #undef STAGE
    #undef ITERL
    #undef PVLOAD_L
    #undef PVACC_L
}

// ---- kernel 4: combine the two packed key-half partials -------------------
__global__ __launch_bounds__(256) void combine_kernel(
        float* __restrict__ out, const float* __restrict__ pm,
        const float* __restrict__ pl) {
    const int idx = blockIdx.x * 256 + threadIdx.x;   // 1M/4 quads
    const int w0 = idx * 4;
    const int q = w0 >> 6;
    u32x4 d = *reinterpret_cast<const u32x4*>(reinterpret_cast<const unsigned int*>(out) + w0);
    const float m0 = pm[q], m1 = pm[16384 + q];
    const float l0 = pl[q], l1 = pl[16384 + q];
    const float M = fmaxf(m0, m1);
    const float e0 = exp2f(m0 - M), e1 = exp2f(m1 - M);
    const float inv = 1.0f / (l0 * e0 + l1 * e1);
    fvec4 r;
    #pragma unroll
    for (int j = 0; j < 4; ++j) {
        float p0 = __builtin_bit_cast(float, d[j] << 16);
        float p1 = __builtin_bit_cast(float, d[j] & 0xffff0000u);
        r[j] = (p0 * e0 + p1 * e1) * inv;
    }
    *reinterpret_cast<fvec4*>(out + w0) = r;
}

extern "C" void kernel_launch(void* const* d_in, const int* in_sizes, int n_in,
                              void* d_out, int out_size, void* d_ws, size_t ws_size,
                              hipStream_t stream) {
    (void)in_sizes; (void)n_in; (void)out_size; (void)ws_size;
    const float* x  = (const float*)d_in[0];
    const float* Wk = (const float*)d_in[1];   // setup_inputs order: x, Wk, Wq, Wv
    const float* Wq = (const float*)d_in[2];
    const float* Wv = (const float*)d_in[3];
    float* out = (float*)d_out;

    unsigned short* ws = (unsigned short*)d_ws;
    unsigned short* qg  = ws;                      // 16384*64 bf16
    unsigned short* kg  = ws + 1048576;            // 16384*64 bf16
    unsigned short* vtg = ws + 2097152;            // 8*64*2048 bf16
    unsigned short* wt  = ws + 3145728;            // 3*64*768 bf16
    float* pm = (float*)((char*)d_ws + 6586368);   // [2][16384]
    float* pl = pm + 32768;                        // [2][16384]

    wt_kernel<<<576, 256, 0, stream>>>(Wq, Wk, Wv, wt);
    proj_kernel<<<256, 768, 0, stream>>>(x, wt, qg, kg, vtg);
    attn_kernel<<<256, 512, 0, stream>>>(qg, kg, vtg, out, pm, pl);
    combine_kernel<<<1024, 256, 0, stream>>>(out, pm, pl);
}

// Round 10
// 60.470 us; speedup vs baseline: 2.2159x; 1.0238x over previous
//
#include <hip/hip_runtime.h>
#include <hip/hip_bf16.h>

// Head: x[8,2048,768] fp32; Wk,Wq,Wv [768,64] fp32 -> out[8,2048,64] fp32
// q=xWq k=xWk v=xWv; att=softmax(q k^T/8); out=att v   (no causal mask)
//
// R10 = R9 with attn split 2x for block-level overlap:
//  - attn: grid 512 (8b x 32qt x 2ks), 256 thr = 4 waves x 16 q-rows; shared
//    K/V LDS tiles (global_load_lds dbuf, XOR swizzle); 2-4 blocks/CU so
//    barrier drains overlap across blocks. Partials bf16-packed into d_out.
//  - proj: unchanged from R9 (W in regs, x staged once, dbuf LDS).

#define SEQ   2048
#define CEMB  768
// 0.125 (1/sqrt(64)) * log2(e): folded into q at proj epilogue
#define SCL 0.18033688011112042f
#define THR 11.0f

typedef __attribute__((ext_vector_type(4))) float f32x4;
typedef __attribute__((ext_vector_type(4))) float fvec4;
typedef __attribute__((ext_vector_type(8))) short short8;
typedef __attribute__((ext_vector_type(4))) short short4v;
typedef __attribute__((ext_vector_type(4))) unsigned short u16x4;
typedef __attribute__((ext_vector_type(2))) unsigned int u32x2;
typedef __attribute__((ext_vector_type(4))) unsigned int u32x4;

#define MFMA32 __builtin_amdgcn_mfma_f32_16x16x32_bf16

__device__ __forceinline__ unsigned short f2bf(float f) {
    unsigned int u = __builtin_bit_cast(unsigned int, f);
    u += 0x7fffu + ((u >> 16) & 1u);   // RNE
    return (unsigned short)(u >> 16);
}
__device__ __forceinline__ unsigned int pack_bf2(float lo, float hi) {
    unsigned int ulo = __builtin_bit_cast(unsigned int, lo);
    unsigned int uhi = __builtin_bit_cast(unsigned int, hi);
    return ((uhi + 0x8000u) & 0xffff0000u) | ((ulo + 0x8000u) >> 16);
}
__device__ __forceinline__ short8 pack8(fvec4 a, fvec4 b) {
    short8 s;
    #pragma unroll
    for (int j = 0; j < 4; ++j) {
        s[j]     = (short)f2bf(a[j]);
        s[4 + j] = (short)f2bf(b[j]);
    }
    return s;
}
__device__ __forceinline__ f32x4 vmax4(f32x4 a, f32x4 b) {
    f32x4 r;
    r[0] = fmaxf(a[0], b[0]); r[1] = fmaxf(a[1], b[1]);
    r[2] = fmaxf(a[2], b[2]); r[3] = fmaxf(a[3], b[3]);
    return r;
}
// async global->LDS, 16B per lane
__device__ __forceinline__ void gl_lds16(const void* g, void* l) {
    __builtin_amdgcn_global_load_lds(
        (const __attribute__((address_space(1))) unsigned int*)g,
        (__attribute__((address_space(3))) unsigned int*)l, 16, 0, 0);
}

// ---------------- kernel 1: W -> W^T bf16  (wt[3][64][768]) ----------------
__global__ void wt_kernel(const float* __restrict__ Wq, const float* __restrict__ Wk,
                          const float* __restrict__ Wv, unsigned short* __restrict__ wt) {
    int idx = blockIdx.x * 256 + threadIdx.x;   // 3*64*768 = 147456
    int o = idx / 49152;
    int r = idx % 49152;
    int n = r / 768;
    int k = r % 768;
    const float* W = (o == 0) ? Wq : (o == 1) ? Wk : Wv;
    wt[idx] = f2bf(W[k * 64 + n]);
}

// ---- kernel 2: proj, 12 waves=(o,f), W in regs, x LDS-staged (dbuf) ------
__global__ __launch_bounds__(768) void proj_kernel(
        const float* __restrict__ x, const unsigned short* __restrict__ wt,
        unsigned short* __restrict__ qg, unsigned short* __restrict__ kg,
        unsigned short* __restrict__ vtg) {
    __shared__ __align__(16) unsigned short xl[2][12288];   // 2 x 16rows x 96slots x 16B

    const int tid = threadIdx.x;
    const int lane = tid & 63;
    const int wv = tid >> 6;      // 0..11
    const int l15 = lane & 15;
    const int lq = lane >> 4;
    const int o = wv >> 2;        // 0=q 1=k 2=v
    const int f = wv & 3;         // 16-col tile
    const int rowbase = blockIdx.x * 64;

    // W^T tile (16 n-rows x 768 k) -> 24 A-frags in registers (96 VGPR)
    short8 wfr[24];
    #pragma unroll
    for (int s = 0; s < 24; ++s)
        wfr[s] = *reinterpret_cast<const short8*>(
            &wt[o * 49152 + (f * 16 + l15) * CEMB + s * 32 + lq * 8]);

    // stage slot geometry (constant per thread): two slots per pass
    const int S0 = tid, S1 = 768 + tid;
    const int r0 = S0 / 96, c0 = S0 - r0 * 96;
    const int r1 = S1 / 96, c1 = S1 - r1 * 96;
    const int d0 = r0 * 1536 + ((c0 ^ (r0 & 7)) << 4);
    const int d1 = r1 * 1536 + ((c1 ^ (r1 & 7)) << 4);

    // prologue: stage tile 0 into xl[0]
    {
        const float* g0 = x + (size_t)(rowbase + r0) * CEMB + c0 * 8;
        const float* g1 = x + (size_t)(rowbase + r1) * CEMB + c1 * 8;
        fvec4 a0 = *reinterpret_cast<const fvec4*>(g0);
        fvec4 a1 = *reinterpret_cast<const fvec4*>(g0 + 4);
        fvec4 b0 = *reinterpret_cast<const fvec4*>(g1);
        fvec4 b1 = *reinterpret_cast<const fvec4*>(g1 + 4);
        *reinterpret_cast<short8*>((char*)&xl[0][0] + d0) = pack8(a0, a1);
        *reinterpret_cast<short8*>((char*)&xl[0][0] + d1) = pack8(b0, b1);
    }
    __syncthreads();

    #pragma unroll
    for (int t = 0; t < 4; ++t) {
        const int cur = t & 1;
        fvec4 pA0, pA1, pB0, pB1;
        if (t < 3) {   // issue next-tile loads early (T14)
            const int base = rowbase + (t + 1) * 16;
            const float* g0 = x + (size_t)(base + r0) * CEMB + c0 * 8;
            const float* g1 = x + (size_t)(base + r1) * CEMB + c1 * 8;
            pA0 = *reinterpret_cast<const fvec4*>(g0);
            pA1 = *reinterpret_cast<const fvec4*>(g0 + 4);
            pB0 = *reinterpret_cast<const fvec4*>(g1);
            pB1 = *reinterpret_cast<const fvec4*>(g1 + 4);
        }

        // compute tile t: acc = W^T(16n x 768) * x-tile^T
        f32x4 acc = f32x4{0.f, 0.f, 0.f, 0.f};
        const char* xb = (const char*)&xl[cur][0];
        const int rswz = l15 & 7;
        #pragma unroll
        for (int s = 0; s < 24; ++s) {
            short8 bf = *reinterpret_cast<const short8*>(
                xb + l15 * 1536 + (((s * 4 + lq) ^ rswz) << 4));
            acc = MFMA32(wfr[s], bf, acc, 0, 0, 0);
        }

        // epilogue: lane holds out[xrow = rowbase+t*16+l15][n = f*16+lq*4+r]
        const int xrow = rowbase + t * 16 + l15;
        if (o < 2) {
            const float sc = o ? 1.f : SCL;
            u16x4 st;
            #pragma unroll
            for (int r = 0; r < 4; ++r) st[r] = f2bf(acc[r] * sc);
            unsigned short* dst = (o ? kg : qg) + (size_t)xrow * 64 + f * 16 + lq * 4;
            *reinterpret_cast<u16x4*>(dst) = st;
        } else {
            const int bb = xrow >> 11;
            const int tt = xrow & 2047;
            #pragma unroll
            for (int r = 0; r < 4; ++r)
                vtg[(size_t)bb * 131072 + (size_t)(f * 16 + lq * 4 + r) * SEQ + tt] =
                    f2bf(acc[r]);
        }

        if (t < 3) {   // write next tile into the other buffer
            *reinterpret_cast<short8*>((char*)&xl[cur ^ 1][0] + d0) = pack8(pA0, pA1);
            *reinterpret_cast<short8*>((char*)&xl[cur ^ 1][0] + d1) = pack8(pB0, pB1);
        }
        __syncthreads();
    }
}

// ---- kernel 3: attn, shared K/V LDS tiles, swapped-QK lane-local softmax --
#if __has_builtin(__builtin_amdgcn_mfma_f32_16x16x16bf16_1k)
#define HAVE_MFMA16 1
#define MFMA16 __builtin_amdgcn_mfma_f32_16x16x16bf16_1k
#else
#define HAVE_MFMA16 0
#endif

__global__ __launch_bounds__(256) void attn_kernel(
        const unsigned short* __restrict__ qg, const unsigned short* __restrict__ kg,
        const unsigned short* __restrict__ vtg, float* __restrict__ out,
        float* __restrict__ pm, float* __restrict__ pl) {
    __shared__ __align__(16) unsigned short kbuf[2][4096];   // [64 key][64 d] swz
    __shared__ __align__(16) unsigned short vbuf[2][4096];   // [64 d][64 key] swz

    const int tid = threadIdx.x;
    const int lane = tid & 63;
    const int wv = tid >> 6;      // q-subtile wave 0..3
    const int l15 = lane & 15;
    const int lq = lane >> 4;

    // XCD swizzle: 512 blocks, 64/XCD = one batch per XCD
    const int swz = (blockIdx.x & 7) * 64 + (blockIdx.x >> 3);
    const int b = swz >> 6;           // batch 0..7
    const int qt = (swz >> 1) & 31;   // 64-row q tile
    const int ks = swz & 1;           // key half
    const int qrow0 = b * SEQ + qt * 64 + wv * 16;

    const unsigned short* kgb = kg + (size_t)(b * SEQ + ks * 1024) * 64;
    const unsigned short* vgb = vtg + (size_t)b * 131072 + ks * 1024;

    // staging geometry: 256 threads x 2 slots x 16B cover one 8KB tile
    const int sr0 = tid >> 3;             // rows 0..31
    const int sw0 = (((tid & 7) ^ (sr0 & 7)) * 8);
    const int sr1 = 32 + sr0;             // rows 32..63
    const int sw1 = (((tid & 7) ^ (sr1 & 7)) * 8);
    #define STAGE(S, KT) do {                                                        \
        gl_lds16(kgb + (size_t)((KT) * 64 + sr0) * 64 + sw0, &kbuf[S][tid * 8]);       \
        gl_lds16(kgb + (size_t)((KT) * 64 + sr1) * 64 + sw1, &kbuf[S][2048 + tid * 8]); \
        gl_lds16(vgb + (size_t)sr0 * SEQ + (KT) * 64 + sw0, &vbuf[S][tid * 8]);        \
        gl_lds16(vgb + (size_t)sr1 * SEQ + (KT) * 64 + sw1, &vbuf[S][2048 + tid * 8]);  \
    } while (0)

    // Q as B-operand (pre-scaled): lane holds Q[q=l15][d slice]
    const short8 bq0 = *reinterpret_cast<const short8*>(&qg[(size_t)(qrow0 + l15) * 64 + lq * 8]);
    const short8 bq1 = *reinterpret_cast<const short8*>(&qg[(size_t)(qrow0 + l15) * 64 + 32 + lq * 8]);

    f32x4 acc[4];
    #pragma unroll
    for (int hb = 0; hb < 4; ++hb) acc[hb] = f32x4{0.f, 0.f, 0.f, 0.f};
    float m = -3e38f, l = 0.f;

    STAGE(0, 0);
    __syncthreads();

    #define ITERL(S) do {                                                            \
        const char* kb_ = (const char*)&kbuf[S][0];                                  \
        const char* vb_ = (const char*)&vbuf[S][0];                                  \
        short8 kf[8];                                                                \
        _Pragma("unroll")                                                            \
        for (int kb = 0; kb < 4; ++kb) {                                             \
            const int row = kb * 16 + l15, rs = row & 7, rb = row * 128;             \
            kf[2 * kb]     = *reinterpret_cast<const short8*>(kb_ + rb + ((lq ^ rs) << 4));       \
            kf[2 * kb + 1] = *reinterpret_cast<const short8*>(kb_ + rb + (((lq + 4) ^ rs) << 4)); \
        }                                                                            \
        PVLOAD_L;                                                                    \
        f32x4 st[4];                                                                 \
        _Pragma("unroll")                                                            \
        for (int kb = 0; kb < 4; ++kb) {                                             \
            f32x4 z = {0.f, 0.f, 0.f, 0.f};                                          \
            st[kb] = MFMA32(kf[2 * kb], bq0, z, 0, 0, 0);                            \
            st[kb] = MFMA32(kf[2 * kb + 1], bq1, st[kb], 0, 0, 0);                   \
        }                                                                            \
        f32x4 mx = vmax4(vmax4(st[0], st[1]), vmax4(st[2], st[3]));                  \
        float p = fmaxf(fmaxf(mx[0], mx[1]), fmaxf(mx[2], mx[3]));                   \
        p = fmaxf(p, __shfl_xor(p, 16)); p = fmaxf(p, __shfl_xor(p, 32));            \
        if (__any(p > m + THR)) {                                                    \
            float mn = fmaxf(m, p);                                                  \
            float al = exp2f(m - mn);                                                \
            m = mn; l *= al;                                                         \
            _Pragma("unroll")                                                        \
            for (int hb = 0; hb < 4; ++hb)                                           \
                _Pragma("unroll")                                                    \
                for (int r = 0; r < 4; ++r) acc[hb][r] *= al;                        \
        }                                                                            \
        unsigned int w[4][2];                                                        \
        _Pragma("unroll")                                                            \
        for (int kb = 0; kb < 4; ++kb) {                                             \
            float e0 = exp2f(st[kb][0] - m), e1 = exp2f(st[kb][1] - m);              \
            float e2 = exp2f(st[kb][2] - m), e3 = exp2f(st[kb][3] - m);              \
            l += (e0 + e1) + (e2 + e3);                                              \
            w[kb][0] = pack_bf2(e0, e1); w[kb][1] = pack_bf2(e2, e3);                \
        }                                                                            \
        PVACC_L;                                                                     \
    } while (0)

#if HAVE_MFMA16
    #define PVLOAD_L                                                                 \
        short4v va[16];                                                              \
        _Pragma("unroll")                                                            \
        for (int hb = 0; hb < 4; ++hb) {                                             \
            const int row = hb * 16 + l15, rs = row & 7, rb = row * 128;             \
            _Pragma("unroll")                                                        \
            for (int kb = 0; kb < 4; ++kb)                                           \
                va[hb * 4 + kb] = *reinterpret_cast<const short4v*>(                 \
                    vb_ + rb + (((kb * 2 + (lq >> 1)) ^ rs) << 4) + (lq & 1) * 8);   \
        }
    #define PVACC_L do {                                                             \
        _Pragma("unroll")                                                            \
        for (int hb = 0; hb < 4; ++hb) {                                             \
            f32x4 a = acc[hb];                                                       \
            _Pragma("unroll")                                                        \
            for (int kb = 0; kb < 4; ++kb) {                                         \
                u32x2 uv; uv[0] = w[kb][0]; uv[1] = w[kb][1];                        \
                a = MFMA16(va[hb * 4 + kb], __builtin_bit_cast(short4v, uv), a, 0, 0, 0); \
            }                                                                        \
            acc[hb] = a;                                                             \
        }                                                                            \
    } while (0)
#else
    #define PVLOAD_L                                                                 \
        short8 va[8];                                                                \
        _Pragma("unroll")                                                            \
        for (int hb = 0; hb < 4; ++hb) {                                             \
            const int row = hb * 16 + l15, rs = row & 7, rb = row * 128;             \
            _Pragma("unroll")                                                        \
            for (int h = 0; h < 2; ++h)                                              \
                va[hb * 2 + h] = *reinterpret_cast<const short8*>(                   \
                    vb_ + rb + (((h * 4 + lq) ^ rs) << 4));                          \
        }
    #define PVACC_L do {                                                             \
        _Pragma("unroll")                                                            \
        for (int h = 0; h < 2; ++h) {                                                \
            u32x4 bw;                                                                \
            _Pragma("unroll")                                                        \
            for (int mw = 0; mw < 4; ++mw) {                                         \
                int src = l15 + ((((lq & 1) * 2) + (mw >> 1)) << 4);                 \
                unsigned int r1 = (unsigned int)__shfl((int)w[h * 2][mw & 1], src);  \
                unsigned int r2 = (unsigned int)__shfl((int)w[h * 2 + 1][mw & 1], src); \
                bw[mw] = (lq >> 1) ? r2 : r1;                                        \
            }                                                                        \
            short8 bp = __builtin_bit_cast(short8, bw);                              \
            _Pragma("unroll")                                                        \
            for (int hb = 0; hb < 4; ++hb)                                           \
                acc[hb] = MFMA32(va[hb * 2 + h], bp, acc[hb], 0, 0, 0);              \
        }                                                                            \
    } while (0)
#endif

    #pragma unroll
    for (int kt2 = 0; kt2 < 8; ++kt2) {
        const int t0 = kt2 * 2;
        if (t0 + 1 < 16) STAGE(1, t0 + 1);
        ITERL(0);
        __syncthreads();
        if (t0 + 2 < 16) STAGE(0, t0 + 2);
        ITERL(1);
        __syncthreads();
    }

    // l across the 4-lane q-group (disjoint key subsets)
    l += __shfl_xor(l, 16); l += __shfl_xor(l, 32);

    // partial write: bf16 halves packed into d_out words (ks selects half)
    const int q = qrow0 + l15;
    char* ob = (char*)out;
    #pragma unroll
    for (int hb = 0; hb < 4; ++hb)
        #pragma unroll
        for (int r = 0; r < 4; ++r) {
            const int col = hb * 16 + lq * 4 + r;
            *reinterpret_cast<unsigned short*>(ob + ((size_t)q * 64 + col) * 4 + ks * 2) =
                f2bf(acc[hb][r]);
        }
    pm[ks * 16384 + q] = m;
    pl[ks * 16384 + q] = l;
    #undef STAGE
    #undef ITERL
    #undef PVLOAD_L
    #undef PVACC_L
}

// ---- kernel 4: combine the two packed key-half partials -------------------
__global__ __launch_bounds__(256) void combine_kernel(
        float* __restrict__ out, const float* __restrict__ pm,
        const float* __restrict__ pl) {
    const int idx = blockIdx.x * 256 + threadIdx.x;   // 1M/4 quads
    const int w0 = idx * 4;
    const int q = w0 >> 6;
    u32x4 d = *reinterpret_cast<const u32x4*>(reinterpret_cast<const unsigned int*>(out) + w0);
    const float m0 = pm[q], m1 = pm[16384 + q];
    const float l0 = pl[q], l1 = pl[16384 + q];
    const float M = fmaxf(m0, m1);
    const float e0 = exp2f(m0 - M), e1 = exp2f(m1 - M);
    const float inv = 1.0f / (l0 * e0 + l1 * e1);
    fvec4 r;
    #pragma unroll
    for (int j = 0; j < 4; ++j) {
        float p0 = __builtin_bit_cast(float, d[j] << 16);
        float p1 = __builtin_bit_cast(float, d[j] & 0xffff0000u);
        r[j] = (p0 * e0 + p1 * e1) * inv;
    }
    *reinterpret_cast<fvec4*>(out + w0) = r;
}

extern "C" void kernel_launch(void* const* d_in, const int* in_sizes, int n_in,
                              void* d_out, int out_size, void* d_ws, size_t ws_size,
                              hipStream_t stream) {
    (void)in_sizes; (void)n_in; (void)out_size; (void)ws_size;
    const float* x  = (const float*)d_in[0];
    const float* Wk = (const float*)d_in[1];   // setup_inputs order: x, Wk, Wq, Wv
    const float* Wq = (const float*)d_in[2];
    const float* Wv = (const float*)d_in[3];
    float* out = (float*)d_out;

    unsigned short* ws = (unsigned short*)d_ws;
    unsigned short* qg  = ws;                      // 16384*64 bf16
    unsigned short* kg  = ws + 1048576;            // 16384*64 bf16
    unsigned short* vtg = ws + 2097152;            // 8*64*2048 bf16
    unsigned short* wt  = ws + 3145728;            // 3*64*768 bf16
    float* pm = (float*)((char*)d_ws + 6586368);   // [2][16384]
    float* pl = pm + 32768;                        // [2][16384]

    wt_kernel<<<576, 256, 0, stream>>>(Wq, Wk, Wv, wt);
    proj_kernel<<<256, 768, 0, stream>>>(x, wt, qg, kg, vtg);
    attn_kernel<<<512, 256, 0, stream>>>(qg, kg, vtg, out, pm, pl);
    combine_kernel<<<1024, 256, 0, stream>>>(out, pm, pl);
}